// Round 1
// 199.887 us; speedup vs baseline: 1.0449x; 1.0449x over previous
//
#include <hip/hip_runtime.h>
#include <hip/hip_bf16.h>
#include <math.h>

#define N_NODES 50000
#define N_EDGES 800000
#define HDIM 64

#define NBUCKET 98        // buckets of 512 nodes: 98*512 = 50176 >= 50000
#define BSHIFT  9
#define BCAP    10240     // mean 8163, sd ~88 -> 23 sigma headroom

typedef short bf16x8 __attribute__((ext_vector_type(8)));
typedef float f32x4  __attribute__((ext_vector_type(4)));
typedef unsigned short ushort_t;

__device__ __forceinline__ ushort_t f2bf(float f) {
    __hip_bfloat16 b = __float2bfloat16(f);
    return *(ushort_t*)&b;
}
__device__ __forceinline__ void unpack8(uint4 u, float* f) {
    f[0] = __uint_as_float(u.x << 16); f[1] = __uint_as_float(u.x & 0xFFFF0000u);
    f[2] = __uint_as_float(u.y << 16); f[3] = __uint_as_float(u.y & 0xFFFF0000u);
    f[4] = __uint_as_float(u.z << 16); f[5] = __uint_as_float(u.z & 0xFFFF0000u);
    f[6] = __uint_as_float(u.w << 16); f[7] = __uint_as_float(u.w & 0xFFFF0000u);
}

// ---------------------------------------------------------------------------
// Prep: [0,3125) features->bf16; [3125,3221) W transpose+convert;
// block 3221: zero bucketFill + scalar + done counter.
// ---------------------------------------------------------------------------
__global__ __launch_bounds__(256) void prep_kernel(
    const float* __restrict__ features, ushort_t* __restrict__ x_bf,
    const float* __restrict__ V, const float* __restrict__ lw,
    ushort_t* __restrict__ Wt, int* __restrict__ bucketFill,
    float* __restrict__ scalar, int* __restrict__ done)
{
    const int b = blockIdx.x;
    const int t = threadIdx.x;
    if (b < 3125) {
        const int i = b * 256 + t;                   // < 800000 float4s
        const float4 v = ((const float4*)features)[i];
        ushort4 o = { f2bf(v.x), f2bf(v.y), f2bf(v.z), f2bf(v.w) };
        *(ushort4*)&x_bf[(size_t)i * 4] = o;
    } else if (b < 3221) {
        const int e = (b - 3125) * 256 + t;          // < 24576
        const int l = e / 12288, r = e % 12288;
        const int n = r / 192, k = r % 192;
        const int sel = k >> 6, i = k & 63;
        const float val = (sel < 2) ? V[l * 8192 + sel * 4096 + i * 64 + n]
                                    : lw[l * 4096 + i * 64 + n];
        Wt[e] = f2bf(val);
    } else {
        if (t < NBUCKET) bucketFill[t] = 0;
        if (t == NBUCKET) scalar[0] = 0.0f;
        if (t == NBUCKET + 1) done[0] = 0;
    }
}

// ---------------------------------------------------------------------------
// K1: bucket scatter. Each block takes 2048 edges, LDS-counts 98 dst-buckets,
// reserves per-(block,bucket) space with one global atomicAdd per bucket,
// appends packed payloads: src(16) | etype(3)<<16 | dstloc(9)<<19.
// ---------------------------------------------------------------------------
__global__ __launch_bounds__(256) void bucket_scatter(
    const int* __restrict__ src, const int* __restrict__ dst,
    const int* __restrict__ etype, int* __restrict__ bucketFill,
    unsigned int* __restrict__ buf)
{
    __shared__ int cnt[NBUCKET];
    __shared__ int base[NBUCKET];
    const int t = threadIdx.x;
    if (t < NBUCKET) cnt[t] = 0;
    __syncthreads();

    int rank[8], bkt[8];
    unsigned pay[8];
    bool valid[8];
#pragma unroll
    for (int k = 0; k < 8; ++k) {
        const int e = blockIdx.x * 2048 + k * 256 + t;
        valid[k] = (e < N_EDGES);
        if (valid[k]) {
            const int d = dst[e];
            const int b = d >> BSHIFT;
            bkt[k] = b;
            pay[k] = (unsigned)src[e] | ((unsigned)etype[e] << 16)
                   | ((unsigned)(d & 511) << 19);
            rank[k] = atomicAdd(&cnt[b], 1);
        }
    }
    __syncthreads();
    if (t < NBUCKET) base[t] = atomicAdd(&bucketFill[t], cnt[t]);
    __syncthreads();
#pragma unroll
    for (int k = 0; k < 8; ++k) {
        if (valid[k]) {
            const int pos = base[bkt[k]] + rank[k];
            if (pos < BCAP) buf[bkt[k] * BCAP + pos] = pay[k];
        }
    }
}

// ---------------------------------------------------------------------------
// K2: per-bucket sort. One block per bucket: hist over 512 local nodes,
// wave-scan, writes row_ptr (coalesced) and final edges into the bucket's
// private contiguous window.
// ---------------------------------------------------------------------------
__global__ __launch_bounds__(256) void bucket_sort(
    const unsigned int* __restrict__ buf, const int* __restrict__ bucketFill,
    unsigned int* __restrict__ edges, int* __restrict__ row_ptr)
{
    __shared__ int hist[512];
    __shared__ int lscan[512];
    __shared__ int cnt2[512];
    __shared__ int sfill[128];
    __shared__ int sbase;
    const int b = blockIdx.x;
    const int t = threadIdx.x;

    hist[t] = 0; hist[t + 256] = 0;
    cnt2[t] = 0; cnt2[t + 256] = 0;
    if (t < NBUCKET) sfill[t] = bucketFill[t];
    else if (t < 128) sfill[t] = 0;
    __syncthreads();

    // exclusive prefix over bucket totals -> this bucket's base offset
    for (int off = 1; off < 128; off <<= 1) {
        int u = (t >= off && t < 128) ? sfill[t - off] : 0;
        __syncthreads();
        if (t < 128) sfill[t] += u;
        __syncthreads();
    }
    const int cntb = min(bucketFill[b], BCAP);
    if (t == 0) sbase = sfill[b] - bucketFill[b];
    __syncthreads();
    const int bb = sbase;

    // pass 1: node histogram
    for (int i = t; i < cntb; i += 256)
        atomicAdd(&hist[buf[b * BCAP + i] >> 19], 1);
    __syncthreads();

    // exclusive scan of 512 node counts: wave 0, 8 chunks of 64
    if (t < 64) {
        int carry = 0;
        for (int c = 0; c < 8; ++c) {
            const int h = hist[c * 64 + t];
            int x = h;
#pragma unroll
            for (int off = 1; off < 64; off <<= 1) {
                int u = __shfl_up(x, off, 64);
                if (t >= off) x += u;
            }
            lscan[c * 64 + t] = carry + x - h;
            carry += __shfl(x, 63, 64);
        }
    }
    __syncthreads();

    // row_ptr (coalesced)
    const int n0 = b << BSHIFT;
    for (int i = t; i < 512; i += 256) {
        const int g = n0 + i;
        if (g < N_NODES) row_ptr[g] = bb + lscan[i];
    }
    if (b == NBUCKET - 1 && t == 0) row_ptr[N_NODES] = bb + cntb;

    // pass 2: final placement within the bucket's contiguous window
    for (int i = t; i < cntb; i += 256) {
        const unsigned p = buf[b * BCAP + i];
        const int d = p >> 19;
        const int r = atomicAdd(&cnt2[d], 1);
        edges[bb + lscan[d] + r] = p & 0x7FFFFu;   // src | etype<<16
    }
}

// ---------------------------------------------------------------------------
// Aggregate v2 (group-per-node, zero cross-lane ops):
//   y[n,b,:] = sum_{e: dst=n} comp[etype_e][b] * x[src_e,:]
// 8-lane group owns one node: lane fo accumulates features [fo*8, fo*8+8)
// for both bases in registers; 4 edges in flight per iteration (MLP).
// 8 nodes/wave, 32 nodes/block -> 1563 blocks. No shuffles, full-lane store.
// ---------------------------------------------------------------------------
__global__ __launch_bounds__(256) void aggregate_bf(
    const ushort_t* __restrict__ x,      // [N,64] bf16
    const unsigned int* __restrict__ edges,
    const int* __restrict__ row_ptr,
    const float* __restrict__ comp_l,    // [8,2] f32
    ushort_t* __restrict__ y)            // [N,128] bf16
{
    const int lane = threadIdx.x & 63;
    const int wv   = threadIdx.x >> 6;
    const int fo   = lane & 7;           // feature octet within the node
    const int g    = lane >> 3;          // node slot within the wave
    const int n    = blockIdx.x * 32 + wv * 8 + g;

    int beg = 0, end = 0;
    if (n < N_NODES) { beg = row_ptr[n]; end = row_ptr[n + 1]; }

    float a0[8], a1[8];
#pragma unroll
    for (int i = 0; i < 8; ++i) { a0[i] = 0.f; a1[i] = 0.f; }

    for (int j = beg; j < end; j += 4) {
        unsigned pk[4];
        float2 c[4];
#pragma unroll
        for (int k = 0; k < 4; ++k) {
            const int jk = j + k;
            const unsigned p = edges[(jk < end) ? jk : (end - 1)];
            pk[k] = p;
            float2 cc = *(const float2*)&comp_l[(p >> 16) * 2];
            if (jk >= end) { cc.x = 0.f; cc.y = 0.f; }
            c[k] = cc;
        }
        uint4 u[4];
#pragma unroll
        for (int k = 0; k < 4; ++k)
            u[k] = *(const uint4*)&x[(size_t)(pk[k] & 0xFFFFu) * 64 + fo * 8];
#pragma unroll
        for (int k = 0; k < 4; ++k) {
            float f[8];
            unpack8(u[k], f);
#pragma unroll
            for (int i = 0; i < 8; ++i) {
                a0[i] = fmaf(c[k].x, f[i], a0[i]);
                a1[i] = fmaf(c[k].y, f[i], a1[i]);
            }
        }
    }

    if (n < N_NODES) {
        uint4 o0, o1;
        o0.x = (unsigned)f2bf(a0[0]) | ((unsigned)f2bf(a0[1]) << 16);
        o0.y = (unsigned)f2bf(a0[2]) | ((unsigned)f2bf(a0[3]) << 16);
        o0.z = (unsigned)f2bf(a0[4]) | ((unsigned)f2bf(a0[5]) << 16);
        o0.w = (unsigned)f2bf(a0[6]) | ((unsigned)f2bf(a0[7]) << 16);
        o1.x = (unsigned)f2bf(a1[0]) | ((unsigned)f2bf(a1[1]) << 16);
        o1.y = (unsigned)f2bf(a1[2]) | ((unsigned)f2bf(a1[3]) << 16);
        o1.z = (unsigned)f2bf(a1[4]) | ((unsigned)f2bf(a1[5]) << 16);
        o1.w = (unsigned)f2bf(a1[6]) | ((unsigned)f2bf(a1[7]) << 16);
        *(uint4*)&y[(size_t)n * 128 + fo * 8]      = o0;
        *(uint4*)&y[(size_t)n * 128 + 64 + fo * 8] = o1;
    }
}

// ---------------------------------------------------------------------------
// MFMA node transform: h[0:64] = U[64x192] @ W[192x64] + bias, U=[y0,y1,x]
// bf16, W in registers (6 frags/wave). Wave w owns output cols [16w,16w+16).
//  !FUSE: writes relu(h) bf16.  FUSE: accumulates h . fc_w into scalar;
//  the last block to finish applies sigmoid and writes the output.
// ---------------------------------------------------------------------------
template <bool FUSE>
__global__ __launch_bounds__(256) void mfma_transform(
    const ushort_t* __restrict__ y_bf,   // [N,128]
    const ushort_t* __restrict__ x_bf,   // [N,64]
    const ushort_t* __restrict__ Wt,     // [64,192] this layer (n-major)
    const float* __restrict__ bias,      // [64] f32
    const float* __restrict__ fcw,       // [N*64] (FUSE)
    ushort_t* __restrict__ xout,         // [N,64] (!FUSE)
    float* __restrict__ scalar,          // [1]    (FUSE)
    const float* __restrict__ fcb,       // [1]    (FUSE)
    int* __restrict__ done,              // [1]    (FUSE)
    float* __restrict__ outp)            // [1]    (FUSE)
{
    __shared__ __align__(16) ushort_t su[64 * 200];   // 200 = 192 + 8 pad
    __shared__ float sred[4];
    const int t = threadIdx.x;
    const int w = t >> 6;
    const int lane = t & 63;
    const int c16 = lane & 15;
    const int quad = lane >> 4;
    const int tile = blockIdx.x;

    bf16x8 wf[6];
#pragma unroll
    for (int kf = 0; kf < 6; ++kf)
        wf[kf] = *(const bf16x8*)&Wt[(w * 16 + c16) * 192 + kf * 32 + quad * 8];
    const float bv = bias[w * 16 + c16];

#pragma unroll
    for (int k = 0; k < 6; ++k) {
        const int cid = t + 256 * k;          // 0..1535
        const int row = cid / 24;
        const int part = cid % 24;
        const int n = tile * 64 + row;
        uint4 v = {0u, 0u, 0u, 0u};
        if (n < N_NODES) {
            v = (part < 16) ? *(const uint4*)&y_bf[(size_t)n * 128 + part * 8]
                            : *(const uint4*)&x_bf[(size_t)n * 64 + (part - 16) * 8];
        }
        *(uint4*)&su[row * 200 + part * 8] = v;
    }
    __syncthreads();

    float fsum = 0.f;
#pragma unroll
    for (int mt = 0; mt < 4; ++mt) {
        f32x4 acc = {bv, bv, bv, bv};
#pragma unroll
        for (int kf = 0; kf < 6; ++kf) {
            const bf16x8 af =
                *(const bf16x8*)&su[(mt * 16 + c16) * 200 + kf * 32 + quad * 8];
            acc = __builtin_amdgcn_mfma_f32_16x16x32_bf16(af, wf[kf], acc, 0, 0, 0);
        }
        const int nodeb = tile * 64 + mt * 16 + quad * 4;
        if (FUSE) {
#pragma unroll
            for (int r = 0; r < 4; ++r) {
                const int n = nodeb + r;
                if (n < N_NODES)
                    fsum += acc[r] * fcw[(size_t)n * 64 + w * 16 + c16];
            }
        } else {
#pragma unroll
            for (int r = 0; r < 4; ++r) {
                const int n = nodeb + r;
                if (n < N_NODES)
                    xout[(size_t)n * 64 + w * 16 + c16] = f2bf(fmaxf(acc[r], 0.f));
            }
        }
    }

    if (FUSE) {
#pragma unroll
        for (int off = 32; off; off >>= 1) fsum += __shfl_down(fsum, off, 64);
        if (lane == 0) sred[w] = fsum;
        __syncthreads();
        if (t == 0) {
            atomicAdd(scalar, sred[0] + sred[1] + sred[2] + sred[3]);
            __threadfence();
            const int ticket = atomicAdd(done, 1);
            if (ticket == (int)gridDim.x - 1) {
                // atomic read-back: coherent view of all prior adds
                const float v = atomicAdd(scalar, 0.0f) + fcb[0];
                outp[0] = 1.0f / (1.0f + expf(-v));
            }
        }
    }
}

// ---------------------------------------------------------------------------
extern "C" void kernel_launch(void* const* d_in, const int* in_sizes, int n_in,
                              void* d_out, int out_size, void* d_ws, size_t ws_size,
                              hipStream_t stream)
{
    const float* features = (const float*)d_in[0];  // [50000, 64]
    const float* V        = (const float*)d_in[1];  // [2, 2, 64, 64]
    const float* comp     = (const float*)d_in[2];  // [2, 8, 2]
    const float* loop_w   = (const float*)d_in[3];  // [2, 64, 64]
    const float* bias     = (const float*)d_in[4];  // [2, 64]
    const float* fc_w     = (const float*)d_in[5];  // [1, 50000*64]
    const float* fc_b     = (const float*)d_in[6];  // [1]
    const int*   src      = (const int*)d_in[7];
    const int*   dst      = (const int*)d_in[8];
    const int*   etype    = (const int*)d_in[9];
    float* out = (float*)d_out;

    char* ws = (char*)d_ws;
    ushort_t*     y_bf    = (ushort_t*)(ws);                 // 12,800,000 B
    ushort_t*     x_bf    = (ushort_t*)(ws + 12800000);      //  6,400,000 B
    ushort_t*     x1_bf   = (ushort_t*)(ws + 19200000);      //  6,400,000 B
    ushort_t*     Wt      = (ushort_t*)(ws + 25600000);      //     49,152 B
    float*        scalar  = (float*)   (ws + 25649152);      //          4 B
    int*          done    = (int*)     (ws + 25649160);      //          4 B
    int*          bucketFill = (int*)  (ws + 25649280);      //        392 B
    int*          row_ptr = (int*)     (ws + 25649792);      //    200,004 B
    unsigned int* edges   = (unsigned int*)(ws + 25849856);  //  3,200,000 B
    unsigned int* buf     = (unsigned int*)(ws + 29049856);  //  4,014,080 B
                                                             // end ~33.1 MB

    const int aggBlocks = (N_NODES + 31) / 32;      // 1563
    const int mtBlocks  = (N_NODES + 63) / 64;      // 782
    const int k1Blocks  = (N_EDGES + 2047) / 2048;  // 391

    // ---- prep (bf16 converts + zero counters) + bucketed CSR build ----
    prep_kernel<<<3222, 256, 0, stream>>>(features, x_bf, V, loop_w, Wt,
                                          bucketFill, scalar, done);
    bucket_scatter<<<k1Blocks, 256, 0, stream>>>(src, dst, etype, bucketFill, buf);
    bucket_sort<<<NBUCKET, 256, 0, stream>>>(buf, bucketFill, edges, row_ptr);

    // ---- layer 0 ----
    aggregate_bf<<<aggBlocks, 256, 0, stream>>>(x_bf, edges, row_ptr, comp, y_bf);
    mfma_transform<false><<<mtBlocks, 256, 0, stream>>>(
        y_bf, x_bf, Wt, bias, nullptr, x1_bf, nullptr, nullptr, nullptr, nullptr);

    // ---- layer 1 + fused FC dot + last-block sigmoid ----
    aggregate_bf<<<aggBlocks, 256, 0, stream>>>(x1_bf, edges, row_ptr, comp + 16, y_bf);
    mfma_transform<true><<<mtBlocks, 256, 0, stream>>>(
        y_bf, x1_bf, Wt + 12288, bias + 64, fc_w, nullptr, scalar, fc_b, done, out);
}